// Round 9
// baseline (709.875 us; speedup 1.0000x reference)
//
#include <hip/hip_runtime.h>

#define NPTS 4096
#define FIN  64
#define FOUT 128
#define KNB  16
#define BATCH 8
#define BN_EPS 1e-5f
#define FINF 1e30f

// ---------------- ws layout (bytes) ----------------
#define OFF_SQ     (0)
#define OFF_IDX    (OFF_SQ + BATCH*NPTS*4)
#define OFF_PART   (OFF_IDX + BATCH*NPTS*KNB*4)      // [512][128] partial sum(y)
#define OFF_PART2  (OFF_PART + 512*FOUT*4)           // [512][128] partial sum(y^2)
#define OFF_UBAR   (OFF_PART2 + 512*FOUT*4)
#define OFF_VT     (OFF_UBAR + BATCH*NPTS*FOUT*4)

// ---------------- fused: sq = sum_f x^2 ; Ubar = (W1-W2)x + b ; Vt = W2 x ----------------
__global__ __launch_bounds__(256) void uvsq_kernel(const float* __restrict__ x, const float* __restrict__ W,
                                                   const float* __restrict__ bias,
                                                   float* __restrict__ ubar, float* __restrict__ vt,
                                                   float* __restrict__ sqout){
  const int t = threadIdx.x, l = t & 63;
  const int w = __builtin_amdgcn_readfirstlane(t >> 6);   // wave-uniform -> W via s_load
  const int bid = blockIdx.x;
  const int b = bid & 7, grp = bid >> 3;                  // batch -> XCD round-robin
  const int n = grp*64 + l;
  const float* xp = x + (size_t)b*FIN*NPTS + n;
  float xc[FIN];
  float s = 0.f;
  #pragma unroll
  for (int f=0; f<FIN; ++f){ xc[f] = xp[(size_t)f*NPTS]; s = fmaf(xc[f], xc[f], s); }
  const size_t bn = (size_t)b*NPTS + n;
  if (w == 0) sqout[bn] = s;
  float* up = ubar + bn*FOUT;
  float* vp = vt   + bn*FOUT;
  for (int o = w*32; o < w*32+32; ++o){
    const float* wr = W + o*2*FIN;
    float a1=0.f, a2=0.f;
    #pragma unroll
    for (int f=0; f<FIN; ++f){ a1 = fmaf(wr[f], xc[f], a1); a2 = fmaf(wr[FIN+f], xc[f], a2); }
    up[o] = a1 - a2 + bias[o];
    vp[o] = a2;
  }
}

// ---------------- fused distances + top-16: 32 rows/block, 4 blocks/CU for TLP ----------------
// Diagnosis r7: per-SIMD VALU issue ~30% => latency-bound at 2 waves/SIMD. Fix: halve the
// row-block -> LDS 33.8KB -> 4 blocks/CU (grid 1024, one round), VGPR target <=128.
// r2-proven chunk protocol (single xt buffer, 2 barriers, reg prefetch) and swizzles kept.
// Per wave: 8 rows; lane (cl=l&15 -> 4 cands, rl=l>>4 -> 2 rows): acc[4][2].
// Selection: 8 lanes/row, each keep-16 of its 512-cand substream (union ⊇ true top-16).
__global__ __launch_bounds__(256,2) void knn_kernel(const float* __restrict__ x, const float* __restrict__ sq,
                                                    int* __restrict__ idxout){
  __shared__ float xt[64*64];     // swizzled candidate features: word c*64 + (f ^ (c&60))
  __shared__ float rowf[32*68];   // [row][f] stride 68 (broadcast reads, 2-way = free)
  __shared__ float dtile[32*68];  // [row][cand] stride 68 (wave-private rows)
  __shared__ float rowsq[32];
  const int t = threadIdx.x;
  const int w = t >> 6;
  const int l = t & 63;
  const int b  = blockIdx.x & 7;       // batch -> XCD (x[b] = 1MB, L2-resident)
  const int n0 = (blockIdx.x >> 3) * 32;
  const int ndiag = n0 & ~63;          // the one chunk containing this block's rows
  const float* xb  = x  + (size_t)b*FIN*NPTS;
  const float* sqb = sq + b*NPTS;

  // stage row features + rowsq
  for (int j=t; j<2048; j+=256){ int row = j & 31, f = j >> 5; rowf[row*68+f] = xb[(size_t)f*NPTS + n0 + row]; }
  if (t < 32) rowsq[t] = sqb[n0 + t];

  // staging constants: thread owns cand group c4 (4 cands), f = it*16 + tf
  const int c4 = (t & 15) << 2;
  const int tf = t >> 4;

  // prologue: chunk 0 -> xt, prefetch chunk 1 into regs
  float4 pre[4];
  #pragma unroll
  for (int it=0; it<4; ++it) pre[it] = *(const float4*)(xb + (size_t)(it*16 + tf)*NPTS + c4);
  #pragma unroll
  for (int it=0; it<4; ++it){
    const int f = it*16 + tf;
    const float4 v = pre[it];
    xt[(c4+0)*64 + (f ^ c4)] = v.x;
    xt[(c4+1)*64 + (f ^ c4)] = v.y;
    xt[(c4+2)*64 + (f ^ c4)] = v.z;
    xt[(c4+3)*64 + (f ^ c4)] = v.w;
  }
  #pragma unroll
  for (int it=0; it<4; ++it) pre[it] = *(const float4*)(xb + (size_t)(it*16 + tf)*NPTS + 64 + c4);

  __syncthreads();                      // rowf, rowsq, xt(chunk 0) ready

  const int cl = l & 15;
  const int rl = l >> 4;
  const int row0 = w*8 + rl*2;
  const float rsq0 = rowsq[row0], rsq1 = rowsq[row0+1];
  const int nself0 = n0 + row0, nself1 = n0 + row0 + 1;

  float val[16]; int idx[16];
  #pragma unroll
  for (int q=0;q<16;++q){ val[q] = FINF; idx[q] = 0; }
  const int selrow = w*8 + (l>>3);      // 8 rows/wave, 8 lanes each
  const int selc   = l & 7;
  const int sbase  = selrow*68 + selc;

  for (int c0=0; c0<NPTS; c0+=64){
    float csq[4];
    #pragma unroll
    for (int jc=0;jc<4;++jc) csq[jc] = sqb[c0 + cl*4 + jc];

    float acc[4][2];
    #pragma unroll
    for (int jc=0;jc<4;++jc){ acc[jc][0]=0.f; acc[jc][1]=0.f; }
    #pragma unroll
    for (int i=0;i<16;++i){             // logical f4 = 4i; physical = 4(i^cl)
      const int fp = ((i ^ cl) << 2);
      float4 xv[4], rf[2];
      #pragma unroll
      for (int jc=0;jc<4;++jc) xv[jc] = *(const float4*)&xt[(cl*4+jc)*64 + fp];
      rf[0] = *(const float4*)&rowf[ row0   *68 + i*4];
      rf[1] = *(const float4*)&rowf[(row0+1)*68 + i*4];
      #pragma unroll
      for (int jc=0;jc<4;++jc){
        #pragma unroll
        for (int jr=0;jr<2;++jr){
          acc[jc][jr] = fmaf(xv[jc].x, rf[jr].x, acc[jc][jr]);
          acc[jc][jr] = fmaf(xv[jc].y, rf[jr].y, acc[jc][jr]);
          acc[jc][jr] = fmaf(xv[jc].z, rf[jr].z, acc[jc][jr]);
          acc[jc][jr] = fmaf(xv[jc].w, rf[jr].w, acc[jc][jr]);
        }
      }
    }

    // d = rsq + csq - 2*dot -> dtile (wave-private rows, no barrier)
    {
      float4 dd;
      dd.x = fmaf(-2.f, acc[0][0], rsq0 + csq[0]);
      dd.y = fmaf(-2.f, acc[1][0], rsq0 + csq[1]);
      dd.z = fmaf(-2.f, acc[2][0], rsq0 + csq[2]);
      dd.w = fmaf(-2.f, acc[3][0], rsq0 + csq[3]);
      if (c0 == ndiag){
        const int c = c0 + cl*4;
        if (c+0 == nself0) dd.x = FINF;
        if (c+1 == nself0) dd.y = FINF;
        if (c+2 == nself0) dd.z = FINF;
        if (c+3 == nself0) dd.w = FINF;
      }
      *(float4*)&dtile[ row0   *68 + cl*4] = dd;
      dd.x = fmaf(-2.f, acc[0][1], rsq1 + csq[0]);
      dd.y = fmaf(-2.f, acc[1][1], rsq1 + csq[1]);
      dd.z = fmaf(-2.f, acc[2][1], rsq1 + csq[2]);
      dd.w = fmaf(-2.f, acc[3][1], rsq1 + csq[3]);
      if (c0 == ndiag){
        const int c = c0 + cl*4;
        if (c+0 == nself1) dd.x = FINF;
        if (c+1 == nself1) dd.y = FINF;
        if (c+2 == nself1) dd.z = FINF;
        if (c+3 == nself1) dd.w = FINF;
      }
      *(float4*)&dtile[(row0+1)*68 + cl*4] = dd;
    }
    // two-phase selection: 8 cands/lane this chunk
    {
      const float thr = val[15];
      unsigned mask = 0;
      #pragma unroll
      for (int j=7;j>=0;--j){
        const float d = dtile[sbase + 8*j];
        mask = (mask << 1) | (d < thr ? 1u : 0u);
      }
      while (mask){
        const int j = __builtin_ctz(mask);
        mask &= mask - 1;
        const float d = dtile[sbase + 8*j];
        if (d < val[15]){
          val[15] = d; idx[15] = c0 + selc + 8*j;
          #pragma unroll
          for (int q=15;q>0;--q){
            const bool s_ = val[q] < val[q-1];
            const float tv = val[q], tu = val[q-1];
            val[q]   = s_ ? tu : tv;
            val[q-1] = s_ ? tv : tu;
            const int iv = idx[q], iu = idx[q-1];
            idx[q]   = s_ ? iu : iv;
            idx[q-1] = s_ ? iv : iu;
          }
        }
      }
    }
    // next chunk staging (r2 protocol: 2 barriers)
    if (c0 + 64 < NPTS){
      __syncthreads();                  // all waves done reading xt
      #pragma unroll
      for (int it=0; it<4; ++it){
        const int f = it*16 + tf;
        const float4 v = pre[it];
        xt[(c4+0)*64 + (f ^ c4)] = v.x;
        xt[(c4+1)*64 + (f ^ c4)] = v.y;
        xt[(c4+2)*64 + (f ^ c4)] = v.z;
        xt[(c4+3)*64 + (f ^ c4)] = v.w;
      }
      const int cn = (c0 + 128) & (NPTS-1);   // wrap: benign valid reads
      #pragma unroll
      for (int it=0; it<4; ++it) pre[it] = *(const float4*)(xb + (size_t)(it*16 + tf)*NPTS + cn + c4);
      __syncthreads();                  // xt ready
    }
  }

  // merge 8 sorted per-lane lists -> top-16 per row (order irrelevant downstream)
  int myidx[2];
  #pragma unroll
  for (int round=0; round<16; ++round){
    float v = val[0]; int ii = idx[0]; int src = selc;
    #pragma unroll
    for (int mm=1; mm<8; mm<<=1){
      const float ov = __shfl_xor(v, mm);
      const int   oi = __shfl_xor(ii, mm);
      const int   os = __shfl_xor(src, mm);
      const bool take = (ov < v) || (ov == v && os < src);
      v = take ? ov : v; ii = take ? oi : ii; src = take ? os : src;
    }
    if (selc == src){
      #pragma unroll
      for (int q=0;q<15;++q){ val[q]=val[q+1]; idx[q]=idx[q+1]; }
      val[15] = FINF;
    }
    if ((round & 7) == selc) myidx[round>>3] = ii;
  }
  {
    const int bn = b*NPTS + n0 + selrow;
    int* op = idxout + (size_t)bn*KNB;
    op[selc]     = myidx[0];
    op[8 + selc] = myidx[1];
  }
}

// ---------------- gather V at neighbors: sel=Ubar+(gamma>=0?max:min), per-block partial stats ----------------
__global__ __launch_bounds__(256) void gather_kernel(const float* __restrict__ vt, const float* __restrict__ ubar,
                                                     const int* __restrict__ idxnb, const float* __restrict__ gamma,
                                                     float* __restrict__ outsel, float* __restrict__ part,
                                                     float* __restrict__ part2){
  __shared__ float red[2*FOUT];
  const int t = threadIdx.x;
  const int o = t & 127;
  const int h = __builtin_amdgcn_readfirstlane(t >> 7);   // wave-uniform point half
  const int bid = blockIdx.x;
  const int b = bid & 7;                                  // batch -> XCD: vt[b]=2MB L2-resident
  const int nblk = (bid >> 3) * 64;
  const float gam = gamma[o];
  const float* vtb = vt + (size_t)b*NPTS*FOUT + o;
  float bs = 0.f, bsq = 0.f;
  for (int p=0; p<8; ++p){
    const int ng = nblk + (h*8 + p)*4;
    float selv[4];
    #pragma unroll
    for (int j=0; j<4; ++j){
      const int n  = ng + j;
      const int bn = b*NPTS + n;
      const int* ip = idxnb + (size_t)bn*KNB;             // wave-uniform -> s_load
      float mx = -FINF, mn = FINF, s1 = 0.f, s2 = 0.f;
      #pragma unroll
      for (int kk=0; kk<KNB; ++kk){
        const int m = ip[kk];
        const float v = vtb[(size_t)m*FOUT];              // 256B coalesced per neighbor
        mx = fmaxf(mx, v); mn = fminf(mn, v); s1 += v; s2 = fmaf(v, v, s2);
      }
      const float c = ubar[(size_t)bn*FOUT + o];
      selv[j] = c + (gam >= 0.f ? mx : mn);
      bs  += fmaf(16.f, c, s1);                           // sum_k y = 16c + S1
      bsq += fmaf(16.f*c, c, fmaf(2.f*c, s1, s2));        // sum_k y^2 = 16c^2 + 2c S1 + S2
    }
    *(float4*)&outsel[((size_t)b*FOUT + o)*NPTS + ng] = make_float4(selv[0],selv[1],selv[2],selv[3]);
  }
  if (h == 1){ red[o] = bs; red[FOUT+o] = bsq; }
  __syncthreads();
  if (h == 0){
    part [bid*FOUT + o] = bs  + red[o];
    part2[bid*FOUT + o] = bsq + red[FOUT+o];
  }
}

// ---------------- fused BN-stats + relu(a*y+c): one block per (b,o) ----------------
__global__ __launch_bounds__(256) void applybn_kernel(float* __restrict__ out, const float* __restrict__ part,
                                                      const float* __restrict__ part2,
                                                      const float* __restrict__ gamma, const float* __restrict__ beta){
  __shared__ float red[8];
  const int bid = blockIdx.x;          // 1024 = 8 b x 128 o
  const int o = bid & 127, b = bid >> 7;
  const int t = threadIdx.x;
  float s1 = part [t*FOUT + o] + part [(t+256)*FOUT + o];
  float s2 = part2[t*FOUT + o] + part2[(t+256)*FOUT + o];
  #pragma unroll
  for (int m=1; m<64; m<<=1){ s1 += __shfl_xor(s1, m); s2 += __shfl_xor(s2, m); }
  const int w = t >> 6, l = t & 63;
  if (l == 0){ red[w] = s1; red[4+w] = s2; }
  __syncthreads();
  s1 = red[0]+red[1]+red[2]+red[3];
  s2 = red[4]+red[5]+red[6]+red[7];
  const float invM = 1.f / (float)(BATCH*NPTS*KNB);
  const float mean = s1 * invM;
  const float var  = s2 * invM - mean*mean;
  const float a = gamma[o] * rsqrtf(var + BN_EPS);
  const float c = beta[o] - mean * a;
  float4* p = (float4*)(out + ((size_t)(b*FOUT + o))*NPTS);
  #pragma unroll
  for (int q=0; q<4; ++q){
    float4 v = p[t + q*256];
    v.x = fmaxf(fmaf(a, v.x, c), 0.f);
    v.y = fmaxf(fmaf(a, v.y, c), 0.f);
    v.z = fmaxf(fmaf(a, v.z, c), 0.f);
    v.w = fmaxf(fmaf(a, v.w, c), 0.f);
    p[t + q*256] = v;
  }
}

extern "C" void kernel_launch(void* const* d_in, const int* in_sizes, int n_in,
                              void* d_out, int out_size, void* d_ws, size_t ws_size,
                              hipStream_t stream){
  const float* x     = (const float*)d_in[0];
  const float* W     = (const float*)d_in[1];
  const float* bias  = (const float*)d_in[2];
  const float* gamma = (const float*)d_in[3];
  const float* beta  = (const float*)d_in[4];
  char* ws = (char*)d_ws;
  float* sq     = (float*)(ws + OFF_SQ);
  int*   idxnb  = (int*)(ws + OFF_IDX);
  float* part   = (float*)(ws + OFF_PART);
  float* part2  = (float*)(ws + OFF_PART2);
  float* ubar   = (float*)(ws + OFF_UBAR);
  float* vt     = (float*)(ws + OFF_VT);
  float* out    = (float*)d_out;

  uvsq_kernel   <<<BATCH*NPTS/64, 256, 0, stream>>>(x, W, bias, ubar, vt, sq);
  knn_kernel    <<<BATCH*NPTS/32, 256, 0, stream>>>(x, sq, idxnb);
  gather_kernel <<<BATCH*NPTS/64, 256, 0, stream>>>(vt, ubar, idxnb, gamma, out, part, part2);
  applybn_kernel<<<BATCH*FOUT,    256, 0, stream>>>(out, part, part2, gamma, beta);
}